// Round 1
// baseline (361.058 us; speedup 1.0000x reference)
//
#include <hip/hip_runtime.h>
#include <math.h>

// Retention (B=4, S=4096, D=256), chunkwise linear-attention formulation.
// L=256 chunk; all fp32.
#define BB 4
#define SS 4096
#define DD 256
#define LL 256
#define NCH (SS / LL)          // 16 chunks
#define GAMMA 0.9865f

// workspace layout (in floats)
#define QS  ((size_t)BB * SS * DD)        // 4194304  (Q~, K~, V each)
#define BSZ ((size_t)BB * SS)             // 16384    (denom)
#define BND ((size_t)BB * NCH * DD)       // 16384    (localVec / carryVec)
#define BNDD ((size_t)BB * NCH * DD * DD) // 4194304  (localMat / carryMat)
#define TSZ ((size_t)BB * NCH * LL * LL)  // 4194304  (scores)

// ---------------------------------------------------------------------------
// 4x4 micro-tile inner product over a 16-deep LDS tile.
__device__ __forceinline__ void micro16(const float (*As)[68], const float (*Bs)[68],
                                        int ty4, int tx4, float acc[4][4]) {
#pragma unroll
  for (int k = 0; k < 16; ++k) {
    float4 a = *reinterpret_cast<const float4*>(&As[k][ty4]);
    float4 b = *reinterpret_cast<const float4*>(&Bs[k][tx4]);
    float ar[4] = {a.x, a.y, a.z, a.w};
    float br[4] = {b.x, b.y, b.z, b.w};
#pragma unroll
    for (int r = 0; r < 4; ++r)
#pragma unroll
      for (int c = 0; c < 4; ++c)
        acc[r][c] = fmaf(ar[r], br[c], acc[r][c]);
  }
}

// ---------------------------------------------------------------------------
// 1) QKV projection: O = (X @ W + bias) * scale.
//    which=0: Q~ = Q/16; which=1: K~ = K / sqrt(c_i); which=2: V.
__global__ __launch_bounds__(256) void proj_kernel(
    const float* __restrict__ xq, const float* __restrict__ xk, const float* __restrict__ xv,
    const float* __restrict__ Wq, const float* __restrict__ bq_,
    const float* __restrict__ Wk, const float* __restrict__ bk_,
    const float* __restrict__ Wv, const float* __restrict__ bv_,
    float* __restrict__ Qo, float* __restrict__ Ko, float* __restrict__ Vo)
{
  const int which = blockIdx.z;
  const float* X    = which == 0 ? xq  : (which == 1 ? xk  : xv);
  const float* W    = which == 0 ? Wq  : (which == 1 ? Wk  : Wv);
  const float* bias = which == 0 ? bq_ : (which == 1 ? bk_ : bv_);
  float* O          = which == 0 ? Qo  : (which == 1 ? Ko  : Vo);
  const int m0 = blockIdx.x * 64, n0 = blockIdx.y * 64;
  __shared__ float As[16][68], Bs[16][68];
  const int tid = threadIdx.x;
  const int tx4 = (tid & 15) * 4, ty4 = (tid >> 4) * 4;
  const int am = tid >> 2, ak4 = (tid & 3) * 4;   // transpose-style A load
  const int bk = tid >> 4, bn4 = (tid & 15) * 4;  // natural B load
  float acc[4][4] = {};
  for (int k0 = 0; k0 < DD; k0 += 16) {
    float4 av = *reinterpret_cast<const float4*>(&X[(size_t)(m0 + am) * DD + k0 + ak4]);
    float4 bv = *reinterpret_cast<const float4*>(&W[(size_t)(k0 + bk) * DD + n0 + bn4]);
    __syncthreads();
    As[ak4 + 0][am] = av.x; As[ak4 + 1][am] = av.y;
    As[ak4 + 2][am] = av.z; As[ak4 + 3][am] = av.w;
    *reinterpret_cast<float4*>(&Bs[bk][bn4]) = bv;
    __syncthreads();
    micro16(As, Bs, ty4, tx4, acc);
  }
#pragma unroll
  for (int r = 0; r < 4; ++r) {
    const int row = m0 + ty4 + r;
    const int i = row & (SS - 1);
    float scale = 1.0f;
    if (which == 0) scale = 1.0f / 16.0f;
    else if (which == 1) {
      float cj = (1.0f - powf(GAMMA, (float)(i + 1))) / (1.0f - GAMMA);
      scale = rsqrtf(cj);
    }
    float4 o;
    o.x = (acc[r][0] + bias[n0 + tx4 + 0]) * scale;
    o.y = (acc[r][1] + bias[n0 + tx4 + 1]) * scale;
    o.z = (acc[r][2] + bias[n0 + tx4 + 2]) * scale;
    o.w = (acc[r][3] + bias[n0 + tx4 + 3]) * scale;
    *reinterpret_cast<float4*>(&O[(size_t)row * DD + n0 + tx4]) = o;
  }
}

// ---------------------------------------------------------------------------
// 2a) per-chunk vector state: localVec[d] = sum_{jl} gamma^(L-1-jl) * K~[t0+jl, d]
__global__ __launch_bounds__(256) void local_vec_kernel(
    const float* __restrict__ Kt, float* __restrict__ lVec)
{
  const int chunk = blockIdx.x;
  const int b = chunk / NCH, c = chunk % NCH;
  const int t0 = c * LL;
  const int tid = threadIdx.x;
  const size_t base = (size_t)(b * SS + t0) * DD + tid;
  const float g = GAMMA, g2 = g * g, g3 = g2 * g, g4 = g2 * g2;
  float s = 0.f;
  for (int jl = 0; jl < LL; jl += 4) {
    float k0v = Kt[base + (size_t)(jl + 0) * DD];
    float k1v = Kt[base + (size_t)(jl + 1) * DD];
    float k2v = Kt[base + (size_t)(jl + 2) * DD];
    float k3v = Kt[base + (size_t)(jl + 3) * DD];
    s = g4 * s + g3 * k0v + g2 * k1v + g * k2v + k3v;
  }
  lVec[(size_t)chunk * DD + tid] = s;
}

// 2b) sequential chunk combine for vector state (carry entering each chunk)
__global__ __launch_bounds__(256) void combine_vec_kernel(
    const float* __restrict__ lVec, float* __restrict__ cVec)
{
  const int b = blockIdx.x;
  const int d = threadIdx.x;
  const float gL = powf(GAMMA, (float)LL);
  float s = 0.f;
  for (int c = 0; c < NCH; ++c) {
    cVec[(size_t)(b * NCH + c) * DD + d] = s;
    s = gL * s + lVec[(size_t)(b * NCH + c) * DD + d];
  }
}

// 2c) rs scan: per chunk, s[d] = carry; per row: s = g*s + K~; rs = dot(Q~, s);
//     denom = max(|rs|, 1)
__global__ __launch_bounds__(256) void rs_scan_kernel(
    const float* __restrict__ Kt, const float* __restrict__ Qt,
    const float* __restrict__ cVec, float* __restrict__ denom)
{
  const int chunk = blockIdx.x;
  const int b = chunk / NCH, c = chunk % NCH;
  const int t0 = c * LL;
  const int tid = threadIdx.x;
  __shared__ float P[8][256];
  __shared__ float rsv[8];
  float s = cVec[(size_t)chunk * DD + tid];
  const size_t rowbase = (size_t)(b * SS + t0) * DD + tid;
  for (int il0 = 0; il0 < LL; il0 += 8) {
#pragma unroll
    for (int r = 0; r < 8; ++r) {
      float kv = Kt[rowbase + (size_t)(il0 + r) * DD];
      s = GAMMA * s + kv;
      float qv = Qt[rowbase + (size_t)(il0 + r) * DD];
      P[r][tid] = qv * s;
    }
    __syncthreads();
    const int rr = tid >> 5, lane = tid & 31;
    float part = 0.f;
#pragma unroll
    for (int j = 0; j < 8; ++j) part += P[rr][lane + 32 * j];
#pragma unroll
    for (int off = 16; off > 0; off >>= 1) part += __shfl_down(part, off, 32);
    if (lane == 0) rsv[rr] = part;
    __syncthreads();
    if (tid < 8)
      denom[(size_t)b * SS + t0 + il0 + tid] = fmaxf(fabsf(rsv[tid]), 1.0f);
    __syncthreads();
  }
}

// ---------------------------------------------------------------------------
// 3a) per-chunk matrix state: lMat[d,e] = sum_jl w(jl) K~[j,d] V[j,e],
//     w(jl) = gamma^(L-1-jl) / denom[j]
__global__ __launch_bounds__(256) void local_mat_kernel(
    const float* __restrict__ Kt, const float* __restrict__ Vv,
    const float* __restrict__ denom, float* __restrict__ lMat)
{
  const int chunk = blockIdx.x;
  const int b = chunk / NCH, c = chunk % NCH;
  const int t0 = c * LL;
  const int m0 = (blockIdx.y >> 2) * 64, n0 = (blockIdx.y & 3) * 64;  // (d,e) tile
  __shared__ float As[16][68], Bs[16][68];
  const int tid = threadIdx.x;
  const int tx4 = (tid & 15) * 4, ty4 = (tid >> 4) * 4;
  const int bk = tid >> 4, bn4 = (tid & 15) * 4;
  float acc[4][4] = {};
  for (int k0 = 0; k0 < LL; k0 += 16) {
    const int j = t0 + k0 + bk;
    const float w = powf(GAMMA, (float)(LL - 1 - (k0 + bk))) / denom[(size_t)b * SS + j];
    float4 av = *reinterpret_cast<const float4*>(&Kt[(size_t)(b * SS + j) * DD + m0 + bn4]);
    float4 bv = *reinterpret_cast<const float4*>(&Vv[(size_t)(b * SS + j) * DD + n0 + bn4]);
    __syncthreads();
    av.x *= w; av.y *= w; av.z *= w; av.w *= w;
    *reinterpret_cast<float4*>(&As[bk][bn4]) = av;
    *reinterpret_cast<float4*>(&Bs[bk][bn4]) = bv;
    __syncthreads();
    micro16(As, Bs, ty4, tx4, acc);
  }
#pragma unroll
  for (int r = 0; r < 4; ++r) {
    float4 o = {acc[r][0], acc[r][1], acc[r][2], acc[r][3]};
    *reinterpret_cast<float4*>(&lMat[((size_t)chunk * DD + m0 + ty4 + r) * DD + n0 + tx4]) = o;
  }
}

// 3b) sequential chunk combine for matrix state
__global__ __launch_bounds__(256) void combine_mat_kernel(
    const float* __restrict__ lMat, float* __restrict__ cMat)
{
  const size_t idx = (size_t)blockIdx.x * 256 + threadIdx.x;  // over B*D*D
  const int b = (int)(idx >> 16);
  const int de = (int)(idx & 65535);
  const float gL = powf(GAMMA, (float)LL);
  float s = 0.f;
  for (int c = 0; c < NCH; ++c) {
    const size_t o = ((size_t)(b * NCH + c) << 16) + de;
    cMat[o] = s;
    s = gL * s + lMat[o];
  }
}

// ---------------------------------------------------------------------------
// 4a) inter-chunk output: out[i,e] = gamma^(il+1) * sum_d Q~[i,d] cMat[b,c,d,e]
//     (overwrites out)
__global__ __launch_bounds__(256) void inter_kernel(
    const float* __restrict__ Qt, const float* __restrict__ cMat, float* __restrict__ out)
{
  const int chunk = blockIdx.x;
  const int b = chunk / NCH, c = chunk % NCH;
  const int t0 = c * LL;
  const int m0 = (blockIdx.y >> 2) * 64, n0 = (blockIdx.y & 3) * 64;
  __shared__ float As[16][68], Bs[16][68];
  const int tid = threadIdx.x;
  const int tx4 = (tid & 15) * 4, ty4 = (tid >> 4) * 4;
  const int am = tid >> 2, ak4 = (tid & 3) * 4;
  const int bk = tid >> 4, bn4 = (tid & 15) * 4;
  float acc[4][4] = {};
  for (int k0 = 0; k0 < DD; k0 += 16) {
    float4 av = *reinterpret_cast<const float4*>(&Qt[(size_t)(b * SS + t0 + m0 + am) * DD + k0 + ak4]);
    float4 bv = *reinterpret_cast<const float4*>(&cMat[((size_t)chunk * DD + k0 + bk) * DD + n0 + bn4]);
    __syncthreads();
    As[ak4 + 0][am] = av.x; As[ak4 + 1][am] = av.y;
    As[ak4 + 2][am] = av.z; As[ak4 + 3][am] = av.w;
    *reinterpret_cast<float4*>(&Bs[bk][bn4]) = bv;
    __syncthreads();
    micro16(As, Bs, ty4, tx4, acc);
  }
#pragma unroll
  for (int r = 0; r < 4; ++r) {
    const int il = m0 + ty4 + r;
    const float sc = powf(GAMMA, (float)(il + 1));
    float4 o = {acc[r][0] * sc, acc[r][1] * sc, acc[r][2] * sc, acc[r][3] * sc};
    *reinterpret_cast<float4*>(&out[(size_t)(b * SS + t0 + il) * DD + n0 + tx4]) = o;
  }
}

// 4b) intra-chunk scores: T[il,jl] = (jl<=il) * dot(Q~_il,K~_jl) * g^(il-jl) / denom[jl]
__global__ __launch_bounds__(256) void scores_kernel(
    const float* __restrict__ Qt, const float* __restrict__ Kt,
    const float* __restrict__ denom, float* __restrict__ T)
{
  const int chunk = blockIdx.x;
  const int b = chunk / NCH, c = chunk % NCH;
  const int t0 = c * LL;
  const int m0 = (blockIdx.y >> 2) * 64, n0 = (blockIdx.y & 3) * 64;
  if (n0 > m0) return;  // fully masked tile; never read by tv_kernel (kmax bound)
  __shared__ float As[16][68], Bs[16][68];
  const int tid = threadIdx.x;
  const int tx4 = (tid & 15) * 4, ty4 = (tid >> 4) * 4;
  const int am = tid >> 2, ak4 = (tid & 3) * 4;
  float acc[4][4] = {};
  const size_t arow = (size_t)(b * SS + t0 + m0 + am) * DD;
  const size_t brow = (size_t)(b * SS + t0 + n0 + am) * DD;
  for (int k0 = 0; k0 < DD; k0 += 16) {
    float4 av = *reinterpret_cast<const float4*>(&Qt[arow + k0 + ak4]);
    float4 bv = *reinterpret_cast<const float4*>(&Kt[brow + k0 + ak4]);
    __syncthreads();
    As[ak4 + 0][am] = av.x; As[ak4 + 1][am] = av.y;
    As[ak4 + 2][am] = av.z; As[ak4 + 3][am] = av.w;
    Bs[ak4 + 0][am] = bv.x; Bs[ak4 + 1][am] = bv.y;
    Bs[ak4 + 2][am] = bv.z; Bs[ak4 + 3][am] = bv.w;
    __syncthreads();
    micro16(As, Bs, ty4, tx4, acc);
  }
#pragma unroll
  for (int r = 0; r < 4; ++r) {
    const int il = m0 + ty4 + r;
    float ov[4];
#pragma unroll
    for (int cc = 0; cc < 4; ++cc) {
      const int jl = n0 + tx4 + cc;
      float v = 0.f;
      if (jl <= il)
        v = acc[r][cc] * powf(GAMMA, (float)(il - jl)) / denom[(size_t)b * SS + t0 + jl];
      ov[cc] = v;
    }
    float4 o = {ov[0], ov[1], ov[2], ov[3]};
    *reinterpret_cast<float4*>(&T[(size_t)chunk * LL * LL + (size_t)il * LL + n0 + tx4]) = o;
  }
}

// 4c) out += T @ V (per chunk); k-loop bounded by causal structure
__global__ __launch_bounds__(256) void tv_kernel(
    const float* __restrict__ T, const float* __restrict__ Vv, float* __restrict__ out)
{
  const int chunk = blockIdx.x;
  const int b = chunk / NCH, c = chunk % NCH;
  const int t0 = c * LL;
  const int m0 = (blockIdx.y >> 2) * 64, n0 = (blockIdx.y & 3) * 64;  // m over L, n over D
  __shared__ float As[16][68], Bs[16][68];
  const int tid = threadIdx.x;
  const int tx4 = (tid & 15) * 4, ty4 = (tid >> 4) * 4;
  const int am = tid >> 2, ak4 = (tid & 3) * 4;
  const int bk = tid >> 4, bn4 = (tid & 15) * 4;
  float acc[4][4] = {};
  const int kmax = (m0 + 64 < LL) ? (m0 + 64) : LL;  // T[il,jl]=0 for jl>il
  for (int k0 = 0; k0 < kmax; k0 += 16) {
    float4 av = *reinterpret_cast<const float4*>(&T[(size_t)chunk * LL * LL + (size_t)(m0 + am) * LL + k0 + ak4]);
    float4 bv = *reinterpret_cast<const float4*>(&Vv[(size_t)(b * SS + t0 + k0 + bk) * DD + n0 + bn4]);
    __syncthreads();
    As[ak4 + 0][am] = av.x; As[ak4 + 1][am] = av.y;
    As[ak4 + 2][am] = av.z; As[ak4 + 3][am] = av.w;
    *reinterpret_cast<float4*>(&Bs[bk][bn4]) = bv;
    __syncthreads();
    micro16(As, Bs, ty4, tx4, acc);
  }
#pragma unroll
  for (int r = 0; r < 4; ++r) {
    float* op = &out[(size_t)(b * SS + t0 + m0 + ty4 + r) * DD + n0 + tx4];
    float4 cur = *reinterpret_cast<float4*>(op);
    cur.x += acc[r][0]; cur.y += acc[r][1];
    cur.z += acc[r][2]; cur.w += acc[r][3];
    *reinterpret_cast<float4*>(op) = cur;
  }
}

// ---------------------------------------------------------------------------
extern "C" void kernel_launch(void* const* d_in, const int* in_sizes, int n_in,
                              void* d_out, int out_size, void* d_ws, size_t ws_size,
                              hipStream_t stream) {
  const float* xq = (const float*)d_in[0];
  const float* xk = (const float*)d_in[1];
  const float* xv = (const float*)d_in[2];
  const float* Wq = (const float*)d_in[3];
  const float* bq = (const float*)d_in[4];
  const float* Wk = (const float*)d_in[5];
  const float* bk = (const float*)d_in[6];
  const float* Wv = (const float*)d_in[7];
  const float* bv = (const float*)d_in[8];
  float* out = (float*)d_out;

  float* ws = (float*)d_ws;
  float* Q     = ws;                 // Q~ = (xq Wq + bq)/16
  float* K     = Q + QS;             // K~ = (xk Wk + bk)/sqrt(c_j)
  float* V     = K + QS;
  float* denom = V + QS;             // B*S
  float* lVec  = denom + BSZ;        // B*NCH*D
  float* cVec  = lVec + BND;         // B*NCH*D
  float* lMat  = cVec + BND;         // B*NCH*D*D
  float* cMat  = lMat + BNDD;        // B*NCH*D*D
  float* T     = cMat + BNDD;        // B*NCH*L*L

  // 1) projections: grid (M/64, N/64, 3)
  proj_kernel<<<dim3(BB * SS / 64, DD / 64, 3), 256, 0, stream>>>(
      xq, xk, xv, Wq, bq, Wk, bk, Wv, bv, Q, K, V);
  // 2) vector-state scan → denom
  local_vec_kernel<<<BB * NCH, 256, 0, stream>>>(K, lVec);
  combine_vec_kernel<<<BB, 256, 0, stream>>>(lVec, cVec);
  rs_scan_kernel<<<BB * NCH, 256, 0, stream>>>(K, Q, cVec, denom);
  // 3) matrix-state scan
  local_mat_kernel<<<dim3(BB * NCH, 16), 256, 0, stream>>>(K, V, denom, lMat);
  combine_mat_kernel<<<(BB * DD * DD) / 256, 256, 0, stream>>>(lMat, cMat);
  // 4) output = inter (overwrite) + intra (scores, then += T@V)
  inter_kernel<<<dim3(BB * NCH, 16), 256, 0, stream>>>(Q, cMat, out);
  scores_kernel<<<dim3(BB * NCH, 16), 256, 0, stream>>>(Q, K, denom, T);
  tv_kernel<<<dim3(BB * NCH, 16), 256, 0, stream>>>(T, V, out);
}

// Round 2
// 298.157 us; speedup vs baseline: 1.2110x; 1.2110x over previous
//
#include <hip/hip_runtime.h>
#include <math.h>

// Retention (B=4, S=4096, D=256), chunkwise formulation, split-bf16 MFMA GEMMs.
#define BB 4
#define SS 4096
#define DD 256
#define LL 256
#define NCH 16
#define GAMMA 0.9865f
#define LDK 40  // padded LDS row (shorts): 80 B = 16B-aligned, 20-dword stride -> 2-way conflicts only

typedef __attribute__((ext_vector_type(8))) short short8;
typedef __attribute__((ext_vector_type(4))) float f32x4;
typedef unsigned short u16;

__device__ __forceinline__ u16 f2bf(float f) {
  union { float f; unsigned u; } v; v.f = f;
  unsigned r = v.u + 0x7FFFu + ((v.u >> 16) & 1u);
  return (u16)(r >> 16);
}
__device__ __forceinline__ float bf2f(u16 h) {
  union { unsigned u; float f; } v; v.u = ((unsigned)h) << 16; return v.f;
}

// ---------------------------------------------------------------------------
// MFMA core: 128x128 block tile, BK=32, 4 waves (64x64 each), split-bf16
// 3-product accumulate.  A in LDS as [m][k], B as [n][k] (both k-contiguous).
__device__ __forceinline__ void mfma_step(
    const u16 (*Ah)[LDK], const u16 (*Al)[LDK],
    const u16 (*Bh)[LDK], const u16 (*Bl)[LDK],
    int wm0, int wn0, int fm, int fq, f32x4 acc[4][4])
{
  short8 ah[4], al[4], bh[4], bl[4];
#pragma unroll
  for (int i = 0; i < 4; ++i) {
    ah[i] = *(const short8*)&Ah[wm0 + i * 16 + fm][fq * 8];
    al[i] = *(const short8*)&Al[wm0 + i * 16 + fm][fq * 8];
    bh[i] = *(const short8*)&Bh[wn0 + i * 16 + fm][fq * 8];
    bl[i] = *(const short8*)&Bl[wn0 + i * 16 + fm][fq * 8];
  }
#pragma unroll
  for (int i = 0; i < 4; ++i)
#pragma unroll
    for (int j = 0; j < 4; ++j) {
      acc[i][j] = __builtin_amdgcn_mfma_f32_16x16x32_bf16(al[i], bh[j], acc[i][j], 0, 0, 0);
      acc[i][j] = __builtin_amdgcn_mfma_f32_16x16x32_bf16(ah[i], bl[j], acc[i][j], 0, 0, 0);
      acc[i][j] = __builtin_amdgcn_mfma_f32_16x16x32_bf16(ah[i], bh[j], acc[i][j], 0, 0, 0);
    }
}

// stage a 128x32 tile from pre-split bf16 global arrays (row-major, ld elems)
__device__ __forceinline__ void stage_split(
    const u16* __restrict__ Gh, const u16* __restrict__ Gl,
    size_t rowbase, size_t ld, int k0, int tid,
    u16 (*Sh)[LDK], u16 (*Sl)[LDK])
{
#pragma unroll
  for (int it = 0; it < 2; ++it) {
    int r = it * 64 + (tid >> 2);
    int cs = (tid & 3) * 8;
    size_t g = rowbase + (size_t)r * ld + k0 + cs;
    *(short8*)&Sh[r][cs] = *(const short8*)&Gh[g];
    *(short8*)&Sl[r][cs] = *(const short8*)&Gl[g];
  }
}

// stage a 128x32 tile from fp32 global with on-the-fly hi/lo split
__device__ __forceinline__ void stage_f32(
    const float* __restrict__ G, size_t rowbase, size_t ld, int k0, int tid,
    u16 (*Sh)[LDK], u16 (*Sl)[LDK])
{
#pragma unroll
  for (int it = 0; it < 2; ++it) {
    int r = it * 64 + (tid >> 2);
    int cs = (tid & 3) * 8;
    const float* src = &G[rowbase + (size_t)r * ld + k0 + cs];
    u16 hs[8], ls[8];
#pragma unroll
    for (int u = 0; u < 8; ++u) {
      float x = src[u];
      u16 h = f2bf(x);
      hs[u] = h; ls[u] = f2bf(x - bf2f(h));
    }
    *(short8*)&Sh[r][cs] = *(short8*)hs;
    *(short8*)&Sl[r][cs] = *(short8*)ls;
  }
}

// ---------------------------------------------------------------------------
// 0) W transpose+split: Wt[n][k] hi/lo  (3 weight matrices)
__global__ __launch_bounds__(256) void transW_kernel(
    const float* __restrict__ Wq, const float* __restrict__ Wk, const float* __restrict__ Wv,
    u16* __restrict__ Wth, u16* __restrict__ Wtl)
{
  const int which = blockIdx.z;
  const float* W = which == 0 ? Wq : (which == 1 ? Wk : Wv);
  const int k0 = blockIdx.x * 64, n0 = blockIdx.y * 64;
  __shared__ float tile[64][68];
  const int tid = threadIdx.x;
#pragma unroll
  for (int it = 0; it < 4; ++it) {
    int rr = it * 16 + (tid >> 4), cseg = (tid & 15) * 4;
    float4 v = *(const float4*)&W[(size_t)(k0 + rr) * DD + n0 + cseg];
    tile[rr][cseg + 0] = v.x; tile[rr][cseg + 1] = v.y;
    tile[rr][cseg + 2] = v.z; tile[rr][cseg + 3] = v.w;
  }
  __syncthreads();
#pragma unroll
  for (int it = 0; it < 2; ++it) {
    int idx = it * 256 + tid;
    int n = idx >> 3, kseg = idx & 7;
    u16 hs[8], ls[8];
#pragma unroll
    for (int u = 0; u < 8; ++u) {
      float x = tile[kseg * 8 + u][n];
      u16 h = f2bf(x); hs[u] = h; ls[u] = f2bf(x - bf2f(h));
    }
    size_t o = (size_t)(which * 256 + n0 + n) * DD + k0 + kseg * 8;
    *(short8*)&Wth[o] = *(short8*)hs;
    *(short8*)&Wtl[o] = *(short8*)ls;
  }
}

// ---------------------------------------------------------------------------
// 1) QKV projection via MFMA: which=0 Q~=(xWq+b)/16 ; 1: K~=(xWk+b)/sqrt(c) ; 2: V
__global__ __launch_bounds__(256) void proj_kernel(
    const float* __restrict__ xq, const float* __restrict__ xk, const float* __restrict__ xv,
    const u16* __restrict__ Wth, const u16* __restrict__ Wtl,
    const float* __restrict__ bq, const float* __restrict__ bk_, const float* __restrict__ bv,
    float* __restrict__ Q32, u16* __restrict__ Qh, u16* __restrict__ Ql,
    float* __restrict__ K32, u16* __restrict__ Kh, u16* __restrict__ Kl,
    float* __restrict__ V32)
{
  const int which = blockIdx.z;
  const float* X    = which == 0 ? xq : (which == 1 ? xk : xv);
  const float* bias = which == 0 ? bq : (which == 1 ? bk_ : bv);
  const int m0 = blockIdx.x * 128, n0 = blockIdx.y * 128;
  __shared__ u16 Ah[128][LDK], Al[128][LDK], Bh[128][LDK], Bl[128][LDK];
  const int tid = threadIdx.x, lane = tid & 63, wave = tid >> 6;
  const int wm0 = (wave >> 1) * 64, wn0 = (wave & 1) * 64;
  const int fm = lane & 15, fq = lane >> 4;
  f32x4 acc[4][4];
#pragma unroll
  for (int i = 0; i < 4; ++i)
#pragma unroll
    for (int j = 0; j < 4; ++j) acc[i][j] = (f32x4){0.f, 0.f, 0.f, 0.f};
  for (int k0 = 0; k0 < DD; k0 += 32) {
    __syncthreads();
    stage_f32(X, (size_t)m0 * DD, DD, k0, tid, Ah, Al);
    stage_split(Wth, Wtl, (size_t)(which * 256 + n0) * DD, DD, k0, tid, Bh, Bl);
    __syncthreads();
    mfma_step(Ah, Al, Bh, Bl, wm0, wn0, fm, fq, acc);
  }
#pragma unroll
  for (int i = 0; i < 4; ++i)
#pragma unroll
    for (int j = 0; j < 4; ++j)
#pragma unroll
      for (int r = 0; r < 4; ++r) {
        int grow = m0 + wm0 + i * 16 + fq * 4 + r;
        int gcol = n0 + wn0 + j * 16 + fm;
        float v = acc[i][j][r] + bias[gcol];
        size_t o = (size_t)grow * DD + gcol;
        if (which == 0) {
          v *= (1.0f / 16.0f);
          Q32[o] = v; u16 h = f2bf(v); Qh[o] = h; Ql[o] = f2bf(v - bf2f(h));
        } else if (which == 1) {
          int i_s = grow & (SS - 1);
          float cj = (1.0f - powf(GAMMA, (float)(i_s + 1))) / (1.0f - GAMMA);
          v *= rsqrtf(cj);
          K32[o] = v; u16 h = f2bf(v); Kh[o] = h; Kl[o] = f2bf(v - bf2f(h));
        } else {
          V32[o] = v;
        }
      }
}

// ---------------------------------------------------------------------------
// 2) vector-state scan -> denom  (fp32, unchanged from round 1)
__global__ __launch_bounds__(256) void local_vec_kernel(
    const float* __restrict__ Kt, float* __restrict__ lVec)
{
  const int chunk = blockIdx.x;
  const int b = chunk / NCH, c = chunk % NCH;
  const int t0 = c * LL;
  const int tid = threadIdx.x;
  const size_t base = (size_t)(b * SS + t0) * DD + tid;
  const float g = GAMMA, g2 = g * g, g3 = g2 * g, g4 = g2 * g2;
  float s = 0.f;
  for (int jl = 0; jl < LL; jl += 4) {
    float k0v = Kt[base + (size_t)(jl + 0) * DD];
    float k1v = Kt[base + (size_t)(jl + 1) * DD];
    float k2v = Kt[base + (size_t)(jl + 2) * DD];
    float k3v = Kt[base + (size_t)(jl + 3) * DD];
    s = g4 * s + g3 * k0v + g2 * k1v + g * k2v + k3v;
  }
  lVec[(size_t)chunk * DD + tid] = s;
}

__global__ __launch_bounds__(256) void combine_vec_kernel(
    const float* __restrict__ lVec, float* __restrict__ cVec)
{
  const int b = blockIdx.x;
  const int d = threadIdx.x;
  const float gL = powf(GAMMA, (float)LL);
  float s = 0.f;
  for (int c = 0; c < NCH; ++c) {
    cVec[(size_t)(b * NCH + c) * DD + d] = s;
    s = gL * s + lVec[(size_t)(b * NCH + c) * DD + d];
  }
}

__global__ __launch_bounds__(256) void rs_scan_kernel(
    const float* __restrict__ Kt, const float* __restrict__ Qt,
    const float* __restrict__ cVec, float* __restrict__ denom)
{
  const int chunk = blockIdx.x;
  const int b = chunk / NCH, c = chunk % NCH;
  const int t0 = c * LL;
  const int tid = threadIdx.x;
  __shared__ float P[8][256];
  __shared__ float rsv[8];
  float s = cVec[(size_t)chunk * DD + tid];
  const size_t rowbase = (size_t)(b * SS + t0) * DD + tid;
  for (int il0 = 0; il0 < LL; il0 += 8) {
#pragma unroll
    for (int r = 0; r < 8; ++r) {
      float kv = Kt[rowbase + (size_t)(il0 + r) * DD];
      s = GAMMA * s + kv;
      float qv = Qt[rowbase + (size_t)(il0 + r) * DD];
      P[r][tid] = qv * s;
    }
    __syncthreads();
    const int rr = tid >> 5, lane = tid & 31;
    float part = 0.f;
#pragma unroll
    for (int j = 0; j < 8; ++j) part += P[rr][lane + 32 * j];
#pragma unroll
    for (int off = 16; off > 0; off >>= 1) part += __shfl_down(part, off, 32);
    if (lane == 0) rsv[rr] = part;
    __syncthreads();
    if (tid < 8)
      denom[(size_t)b * SS + t0 + il0 + tid] = fmaxf(fabsf(rsv[tid]), 1.0f);
    __syncthreads();
  }
}

// ---------------------------------------------------------------------------
// 3) transposes: K~^T hi/lo ; V^T hi/lo and Vw^T hi/lo (w = g^(L-1-jl)/denom)
__global__ __launch_bounds__(256) void transK_kernel(
    const float* __restrict__ K32, u16* __restrict__ KTh, u16* __restrict__ KTl)
{
  const int sblk = blockIdx.x;            // over B*S/64
  const int b = sblk >> 6, s0 = (sblk & 63) * 64;
  const int d0 = blockIdx.y * 64;
  __shared__ float tile[64][68];
  const int tid = threadIdx.x;
#pragma unroll
  for (int it = 0; it < 4; ++it) {
    int rr = it * 16 + (tid >> 4), cseg = (tid & 15) * 4;
    float4 v = *(const float4*)&K32[(size_t)(b * SS + s0 + rr) * DD + d0 + cseg];
    tile[rr][cseg + 0] = v.x; tile[rr][cseg + 1] = v.y;
    tile[rr][cseg + 2] = v.z; tile[rr][cseg + 3] = v.w;
  }
  __syncthreads();
#pragma unroll
  for (int it = 0; it < 2; ++it) {
    int idx = it * 256 + tid;
    int d = idx >> 3, sseg = idx & 7;
    u16 hs[8], ls[8];
#pragma unroll
    for (int u = 0; u < 8; ++u) {
      float x = tile[sseg * 8 + u][d];
      u16 h = f2bf(x); hs[u] = h; ls[u] = f2bf(x - bf2f(h));
    }
    size_t o = (size_t)(b * DD + d0 + d) * SS + s0 + sseg * 8;
    *(short8*)&KTh[o] = *(short8*)hs;
    *(short8*)&KTl[o] = *(short8*)ls;
  }
}

__global__ __launch_bounds__(256) void transV_kernel(
    const float* __restrict__ V32, const float* __restrict__ denom,
    u16* __restrict__ VTh, u16* __restrict__ VTl,
    u16* __restrict__ VwTh, u16* __restrict__ VwTl)
{
  const int sblk = blockIdx.x;
  const int b = sblk >> 6, s0 = (sblk & 63) * 64;
  const int d0 = blockIdx.y * 64;
  __shared__ float tile[64][68];
  const int tid = threadIdx.x;
#pragma unroll
  for (int it = 0; it < 4; ++it) {
    int rr = it * 16 + (tid >> 4), cseg = (tid & 15) * 4;
    float4 v = *(const float4*)&V32[(size_t)(b * SS + s0 + rr) * DD + d0 + cseg];
    tile[rr][cseg + 0] = v.x; tile[rr][cseg + 1] = v.y;
    tile[rr][cseg + 2] = v.z; tile[rr][cseg + 3] = v.w;
  }
  __syncthreads();
#pragma unroll
  for (int it = 0; it < 2; ++it) {
    int idx = it * 256 + tid;
    int d = idx >> 3, sseg = idx & 7;
    u16 hs[8], ls[8], whs[8], wls[8];
#pragma unroll
    for (int u = 0; u < 8; ++u) {
      int sg = s0 + sseg * 8 + u;
      float x = tile[sseg * 8 + u][d];
      u16 h = f2bf(x); hs[u] = h; ls[u] = f2bf(x - bf2f(h));
      int jl = sg & (LL - 1);
      float w = powf(GAMMA, (float)(LL - 1 - jl)) / denom[(size_t)b * SS + sg];
      float xw = x * w;
      u16 wh = f2bf(xw); whs[u] = wh; wls[u] = f2bf(xw - bf2f(wh));
    }
    size_t o = (size_t)(b * DD + d0 + d) * SS + s0 + sseg * 8;
    *(short8*)&VTh[o]  = *(short8*)hs;  *(short8*)&VTl[o]  = *(short8*)ls;
    *(short8*)&VwTh[o] = *(short8*)whs; *(short8*)&VwTl[o] = *(short8*)wls;
  }
}

// ---------------------------------------------------------------------------
// 4) intra-chunk scores -> T (split bf16).  3 tiles/chunk (causal).
__global__ __launch_bounds__(256) void scores_kernel(
    const u16* __restrict__ Qh, const u16* __restrict__ Ql,
    const u16* __restrict__ Kh, const u16* __restrict__ Kl,
    const float* __restrict__ denom, u16* __restrict__ Th, u16* __restrict__ Tl)
{
  const int chunk = blockIdx.x, b = chunk >> 4, c = chunk & 15;
  const int t0 = c * LL;
  const int ty = blockIdx.y;
  const int m0 = (ty == 0) ? 0 : 128;
  const int n0 = (ty == 2) ? 128 : 0;
  __shared__ u16 Ah[128][LDK], Al[128][LDK], Bh[128][LDK], Bl[128][LDK];
  const int tid = threadIdx.x, lane = tid & 63, wave = tid >> 6;
  const int wm0 = (wave >> 1) * 64, wn0 = (wave & 1) * 64;
  const int fm = lane & 15, fq = lane >> 4;
  f32x4 acc[4][4];
#pragma unroll
  for (int i = 0; i < 4; ++i)
#pragma unroll
    for (int j = 0; j < 4; ++j) acc[i][j] = (f32x4){0.f, 0.f, 0.f, 0.f};
  const size_t abase = (size_t)(b * SS + t0 + m0) * DD;
  const size_t bbase = (size_t)(b * SS + t0 + n0) * DD;
  for (int k0 = 0; k0 < DD; k0 += 32) {
    __syncthreads();
    stage_split(Qh, Ql, abase, DD, k0, tid, Ah, Al);
    stage_split(Kh, Kl, bbase, DD, k0, tid, Bh, Bl);
    __syncthreads();
    mfma_step(Ah, Al, Bh, Bl, wm0, wn0, fm, fq, acc);
  }
#pragma unroll
  for (int i = 0; i < 4; ++i)
#pragma unroll
    for (int j = 0; j < 4; ++j)
#pragma unroll
      for (int r = 0; r < 4; ++r) {
        int il = m0 + wm0 + i * 16 + fq * 4 + r;
        int jl = n0 + wn0 + j * 16 + fm;
        float v = 0.f;
        if (jl <= il)
          v = acc[i][j][r] * powf(GAMMA, (float)(il - jl)) / denom[(size_t)b * SS + t0 + jl];
        size_t o = (size_t)chunk * LL * LL + (size_t)il * LL + jl;
        u16 h = f2bf(v); Th[o] = h; Tl[o] = f2bf(v - bf2f(h));
      }
}

// 5) per-chunk matrix state (transposed): lMatT[e][d] = sum_j Vw[j,e] K~[j,d]
__global__ __launch_bounds__(256) void lmat_kernel(
    const u16* __restrict__ VwTh, const u16* __restrict__ VwTl,
    const u16* __restrict__ KTh, const u16* __restrict__ KTl,
    float* __restrict__ lMatT)
{
  const int chunk = blockIdx.x, b = chunk >> 4, c = chunk & 15;
  const int t0 = c * LL;
  const int ty = blockIdx.y;
  const int m0 = (ty >> 1) * 128, n0 = (ty & 1) * 128;
  __shared__ u16 Ah[128][LDK], Al[128][LDK], Bh[128][LDK], Bl[128][LDK];
  const int tid = threadIdx.x, lane = tid & 63, wave = tid >> 6;
  const int wm0 = (wave >> 1) * 64, wn0 = (wave & 1) * 64;
  const int fm = lane & 15, fq = lane >> 4;
  f32x4 acc[4][4];
#pragma unroll
  for (int i = 0; i < 4; ++i)
#pragma unroll
    for (int j = 0; j < 4; ++j) acc[i][j] = (f32x4){0.f, 0.f, 0.f, 0.f};
  const size_t abase = (size_t)(b * DD + m0) * SS + t0;
  const size_t bbase = (size_t)(b * DD + n0) * SS + t0;
  for (int k0 = 0; k0 < LL; k0 += 32) {
    __syncthreads();
    stage_split(VwTh, VwTl, abase, SS, k0, tid, Ah, Al);
    stage_split(KTh, KTl, bbase, SS, k0, tid, Bh, Bl);
    __syncthreads();
    mfma_step(Ah, Al, Bh, Bl, wm0, wn0, fm, fq, acc);
  }
#pragma unroll
  for (int i = 0; i < 4; ++i)
#pragma unroll
    for (int j = 0; j < 4; ++j)
#pragma unroll
      for (int r = 0; r < 4; ++r) {
        int e = m0 + wm0 + i * 16 + fq * 4 + r;
        int d = n0 + wn0 + j * 16 + fm;
        lMatT[(size_t)chunk * DD * DD + (size_t)e * DD + d] = acc[i][j][r];
      }
}

// 6) chunk combine for matrix state -> carry as split bf16
__global__ __launch_bounds__(256) void combine_mat_kernel(
    const float* __restrict__ lMatT, u16* __restrict__ cMh, u16* __restrict__ cMl)
{
  const size_t idx = (size_t)blockIdx.x * 256 + threadIdx.x;  // B*D*D
  const int b = (int)(idx >> 16);
  const int ed = (int)(idx & 65535);
  const float gL = powf(GAMMA, (float)LL);
  float s = 0.f;
  for (int c = 0; c < NCH; ++c) {
    const size_t o = ((size_t)(b * NCH + c) << 16) + ed;
    u16 h = f2bf(s); cMh[o] = h; cMl[o] = f2bf(s - bf2f(h));
    s = gL * s + lMatT[o];
  }
}

// 7) output = gamma^(il+1) * Q~ @ cMatT^T  +  T @ V  (fused, overwrite)
__global__ __launch_bounds__(256) void out_kernel(
    const u16* __restrict__ Qh, const u16* __restrict__ Ql,
    const u16* __restrict__ cMh, const u16* __restrict__ cMl,
    const u16* __restrict__ Th, const u16* __restrict__ Tl,
    const u16* __restrict__ VTh, const u16* __restrict__ VTl,
    float* __restrict__ out)
{
  const int chunk = blockIdx.x, b = chunk >> 4, c = chunk & 15;
  const int t0 = c * LL;
  const int ty = blockIdx.y;
  const int m0 = (ty >> 1) * 128, n0 = (ty & 1) * 128;
  __shared__ u16 Ah[128][LDK], Al[128][LDK], Bh[128][LDK], Bl[128][LDK];
  const int tid = threadIdx.x, lane = tid & 63, wave = tid >> 6;
  const int wm0 = (wave >> 1) * 64, wn0 = (wave & 1) * 64;
  const int fm = lane & 15, fq = lane >> 4;
  f32x4 acc[4][4];
#pragma unroll
  for (int i = 0; i < 4; ++i)
#pragma unroll
    for (int j = 0; j < 4; ++j) acc[i][j] = (f32x4){0.f, 0.f, 0.f, 0.f};
  // loop 1: inter-chunk  (A = Q~ rows, B = cMatT rows [e][d])
  {
    const size_t abase = (size_t)(b * SS + t0 + m0) * DD;
    const size_t bbase = (size_t)chunk * DD * DD + (size_t)n0 * DD;
    for (int k0 = 0; k0 < DD; k0 += 32) {
      __syncthreads();
      stage_split(Qh, Ql, abase, DD, k0, tid, Ah, Al);
      stage_split(cMh, cMl, bbase, DD, k0, tid, Bh, Bl);
      __syncthreads();
      mfma_step(Ah, Al, Bh, Bl, wm0, wn0, fm, fq, acc);
    }
  }
  // scale inter part by gamma^(il+1)
#pragma unroll
  for (int i = 0; i < 4; ++i)
#pragma unroll
    for (int r = 0; r < 4; ++r) {
      int il = m0 + wm0 + i * 16 + fq * 4 + r;
      float sc = powf(GAMMA, (float)(il + 1));
#pragma unroll
      for (int j = 0; j < 4; ++j) acc[i][j][r] *= sc;
    }
  // loop 2: intra-chunk  (A = T rows [il][jl], B = V^T rows [e][s])
  {
    const size_t abase = (size_t)chunk * LL * LL + (size_t)m0 * LL;
    const size_t bbase = (size_t)(b * DD + n0) * SS + t0;
    const int kmax = m0 + 128;  // T[il][jl]=0 for jl>il
    for (int k0 = 0; k0 < kmax; k0 += 32) {
      __syncthreads();
      stage_split(Th, Tl, abase, LL, k0, tid, Ah, Al);
      stage_split(VTh, VTl, bbase, SS, k0, tid, Bh, Bl);
      __syncthreads();
      mfma_step(Ah, Al, Bh, Bl, wm0, wn0, fm, fq, acc);
    }
  }
#pragma unroll
  for (int i = 0; i < 4; ++i)
#pragma unroll
    for (int j = 0; j < 4; ++j)
#pragma unroll
      for (int r = 0; r < 4; ++r) {
        int il = m0 + wm0 + i * 16 + fq * 4 + r;
        int e  = n0 + wn0 + j * 16 + fm;
        out[(size_t)(b * SS + t0 + il) * DD + e] = acc[i][j][r];
      }
}

// ---------------------------------------------------------------------------
extern "C" void kernel_launch(void* const* d_in, const int* in_sizes, int n_in,
                              void* d_out, int out_size, void* d_ws, size_t ws_size,
                              hipStream_t stream) {
  const float* xq = (const float*)d_in[0];
  const float* xk = (const float*)d_in[1];
  const float* xv = (const float*)d_in[2];
  const float* Wq = (const float*)d_in[3];
  const float* bq = (const float*)d_in[4];
  const float* Wk = (const float*)d_in[5];
  const float* bk = (const float*)d_in[6];
  const float* Wv = (const float*)d_in[7];
  const float* bv = (const float*)d_in[8];
  float* out = (float*)d_out;

  char* p = (char*)d_ws;
  const size_t F32 = (size_t)BB * SS * DD * 4;   // 16 MB
  const size_t H16 = (size_t)BB * SS * DD * 2;   // 8 MB
  float* Q32 = (float*)p; p += F32;
  float* K32 = (float*)p; p += F32;
  float* V32 = (float*)p; p += F32;
  float* lMatT = (float*)p; p += F32;
  u16* Qh = (u16*)p; p += H16;  u16* Ql = (u16*)p; p += H16;
  u16* Kh = (u16*)p; p += H16;  u16* Kl = (u16*)p; p += H16;
  u16* KTh = (u16*)p; p += H16; u16* KTl = (u16*)p; p += H16;
  u16* VTh = (u16*)p; p += H16; u16* VTl = (u16*)p; p += H16;
  u16* VwTh = (u16*)p; p += H16; u16* VwTl = (u16*)p; p += H16;
  u16* cMh = (u16*)p; p += H16; u16* cMl = (u16*)p; p += H16;
  u16* Th = (u16*)p; p += H16;  u16* Tl = (u16*)p; p += H16;
  u16* Wth = (u16*)p; p += (size_t)3 * 256 * 256 * 2;
  u16* Wtl = (u16*)p; p += (size_t)3 * 256 * 256 * 2;
  float* denom = (float*)p; p += (size_t)BB * SS * 4;
  float* lVec = (float*)p; p += (size_t)BB * NCH * DD * 4;
  float* cVec = (float*)p; p += (size_t)BB * NCH * DD * 4;

  transW_kernel<<<dim3(4, 4, 3), 256, 0, stream>>>(Wq, Wk, Wv, Wth, Wtl);
  proj_kernel<<<dim3(BB * SS / 128, 2, 3), 256, 0, stream>>>(
      xq, xk, xv, Wth, Wtl, bq, bk, bv, Q32, Qh, Ql, K32, Kh, Kl, V32);
  local_vec_kernel<<<BB * NCH, 256, 0, stream>>>(K32, lVec);
  combine_vec_kernel<<<BB, 256, 0, stream>>>(lVec, cVec);
  rs_scan_kernel<<<BB * NCH, 256, 0, stream>>>(K32, Q32, cVec, denom);
  transK_kernel<<<dim3(BB * SS / 64, 4), 256, 0, stream>>>(K32, KTh, KTl);
  transV_kernel<<<dim3(BB * SS / 64, 4), 256, 0, stream>>>(V32, denom, VTh, VTl, VwTh, VwTl);
  scores_kernel<<<dim3(BB * NCH, 3), 256, 0, stream>>>(Qh, Ql, Kh, Kl, denom, Th, Tl);
  lmat_kernel<<<dim3(BB * NCH, 4), 256, 0, stream>>>(VwTh, VwTl, KTh, KTl, lMatT);
  combine_mat_kernel<<<(BB * DD * DD) / 256, 256, 0, stream>>>(lMatT, cMh, cMl);
  out_kernel<<<dim3(BB * NCH, 4), 256, 0, stream>>>(Qh, Ql, cMh, cMl, Th, Tl, VTh, VTl, out);
}

// Round 3
// 255.759 us; speedup vs baseline: 1.4117x; 1.1658x over previous
//
#include <hip/hip_runtime.h>
#include <math.h>

// Retention (B=4, S=4096, D=256): chunkwise, split-bf16 MFMA, packed k8-slab
// operand layout staged via global_load_lds.
#define BB 4
#define SS 4096
#define DD 256
#define LL 256
#define NCH 16
#define GAMMA 0.9865f
#define LOG2G (-0.019609034f)   // log2(0.9865)
#define INV1MG 74.07407407f     // 1/(1-gamma)

typedef __attribute__((ext_vector_type(8))) short short8;
typedef __attribute__((ext_vector_type(4))) float f32x4;
typedef unsigned short u16;
typedef unsigned int u32;

__device__ __forceinline__ u16 f2bf(float f) {
  union { float f; unsigned u; } v; v.f = f;
  unsigned r = v.u + 0x7FFFu + ((v.u >> 16) & 1u);
  return (u16)(r >> 16);
}
__device__ __forceinline__ float bf2f(u16 h) {
  union { unsigned u; float f; } v; v.u = ((unsigned)h) << 16; return v.f;
}

// async global->LDS, 16B per lane; LDS dest = wave-uniform base + lane*16
__device__ __forceinline__ void gll16(const u16* g, u16* l) {
  __builtin_amdgcn_global_load_lds(
      (const __attribute__((address_space(1))) u32*)g,
      (__attribute__((address_space(3))) u32*)l, 16, 0, 0);
}
// stage 8KB = 4 slabs (one BK=32 k-step of a 128-row panel), one wave
__device__ __forceinline__ void stage8k(const u16* g, u16* l, int lane) {
#pragma unroll
  for (int i = 0; i < 8; ++i)
    gll16(g + i * 512 + lane * 8, l + i * 512);
}

// MFMA: 128x128 tile, BK=32, 4 waves (64x64), split-bf16 3-product.
// LDS layout: [k8(4)][row(128)][8] u16.
__device__ __forceinline__ void mfma_step_slab(
    const u16* Ah, const u16* Al, const u16* Bh, const u16* Bl,
    int wm0, int wn0, int fm, int fq, f32x4 acc[4][4])
{
  short8 ah[4], al[4], bh[4], bl[4];
  const int ka = fq * 1024;
#pragma unroll
  for (int i = 0; i < 4; ++i) {
    ah[i] = *(const short8*)&Ah[ka + (wm0 + i * 16 + fm) * 8];
    al[i] = *(const short8*)&Al[ka + (wm0 + i * 16 + fm) * 8];
    bh[i] = *(const short8*)&Bh[ka + (wn0 + i * 16 + fm) * 8];
    bl[i] = *(const short8*)&Bl[ka + (wn0 + i * 16 + fm) * 8];
  }
#pragma unroll
  for (int i = 0; i < 4; ++i)
#pragma unroll
    for (int j = 0; j < 4; ++j) {
      acc[i][j] = __builtin_amdgcn_mfma_f32_16x16x32_bf16(al[i], bh[j], acc[i][j], 0, 0, 0);
      acc[i][j] = __builtin_amdgcn_mfma_f32_16x16x32_bf16(ah[i], bl[j], acc[i][j], 0, 0, 0);
      acc[i][j] = __builtin_amdgcn_mfma_f32_16x16x32_bf16(ah[i], bh[j], acc[i][j], 0, 0, 0);
    }
}

// ---------------------------------------------------------------------------
// 0) pack W^T (rows n, k d) into slab layout, split hi/lo
__global__ __launch_bounds__(256) void packW_kernel(
    const float* __restrict__ Wq, const float* __restrict__ Wk, const float* __restrict__ Wv,
    u16* __restrict__ Wth, u16* __restrict__ Wtl)
{
  const int which = blockIdx.x, pn = blockIdx.y;
  const float* W = which == 0 ? Wq : (which == 1 ? Wk : Wv);
  const int t = threadIdx.x;
  for (int it = 0; it < 16; ++it) {
    int pos = it * 256 + t;
    int k8 = pos >> 7, r = pos & 127;
    u16 hs[8], ls[8];
#pragma unroll
    for (int u = 0; u < 8; ++u) {
      float x = W[(size_t)(k8 * 8 + u) * DD + pn * 128 + r];
      u16 h = f2bf(x); hs[u] = h; ls[u] = f2bf(x - bf2f(h));
    }
    size_t o = ((size_t)((which * 2 + pn) * 32 + k8)) * 1024 + (size_t)r * 8;
    *(short8*)&Wth[o] = *(short8*)hs;
    *(short8*)&Wtl[o] = *(short8*)ls;
  }
}

// ---------------------------------------------------------------------------
// 1) projections: Q~=(xWq+b)/16, K~=(xWk+b)/sqrt(c), V.  Outputs packed.
__global__ __launch_bounds__(256) void proj_kernel(
    const float* __restrict__ xq, const float* __restrict__ xk, const float* __restrict__ xv,
    const u16* __restrict__ Wth, const u16* __restrict__ Wtl,
    const float* __restrict__ bq, const float* __restrict__ bk_, const float* __restrict__ bv,
    u16* __restrict__ Qh, u16* __restrict__ Ql,
    u16* __restrict__ Kh, u16* __restrict__ Kl,
    u16* __restrict__ KTh, u16* __restrict__ KTl, float* __restrict__ VT32)
{
  const int which = blockIdx.z;
  const float* X    = which == 0 ? xq : (which == 1 ? xk : xv);
  const float* bias = which == 0 ? bq : (which == 1 ? bk_ : bv);
  const int m0 = blockIdx.x * 128;  // global row over B*S
  const int pn = blockIdx.y;        // output n-panel
  __shared__ u16 Ah[4096], Al[4096], Bh[4096], Bl[4096];
  const int tid = threadIdx.x, lane = tid & 63, wave = tid >> 6;
  const int wm0 = (wave >> 1) * 64, wn0 = (wave & 1) * 64;
  const int fm = lane & 15, fq = lane >> 4;
  const u16* WhP = Wth + (size_t)((which * 2 + pn) * 32) * 1024;
  const u16* WlP = Wtl + (size_t)((which * 2 + pn) * 32) * 1024;
  f32x4 acc[4][4];
#pragma unroll
  for (int i = 0; i < 4; ++i)
#pragma unroll
    for (int j = 0; j < 4; ++j) acc[i][j] = (f32x4){0.f, 0.f, 0.f, 0.f};
  for (int ks = 0; ks < 8; ++ks) {
    __syncthreads();
    if (wave == 0) stage8k(WhP + ks * 4096, Bh, lane);
    if (wave == 1) stage8k(WlP + ks * 4096, Bl, lane);
#pragma unroll
    for (int it = 0; it < 2; ++it) {
      int pos = it * 256 + tid;
      int k8l = pos & 3, row = pos >> 2;
      const float* src = &X[(size_t)(m0 + row) * DD + ks * 32 + k8l * 8];
      u16 hs[8], ls[8];
#pragma unroll
      for (int u = 0; u < 8; ++u) {
        float x = src[u];
        u16 h = f2bf(x); hs[u] = h; ls[u] = f2bf(x - bf2f(h));
      }
      *(short8*)&Ah[(k8l * 128 + row) * 8] = *(short8*)hs;
      *(short8*)&Al[(k8l * 128 + row) * 8] = *(short8*)ls;
    }
    __syncthreads();
    mfma_step_slab(Ah, Al, Bh, Bl, wm0, wn0, fm, fq, acc);
  }
#pragma unroll
  for (int i = 0; i < 4; ++i)
#pragma unroll
    for (int j = 0; j < 4; ++j) {
      const int grow0 = m0 + wm0 + i * 16 + fq * 4;
      const int gcol = pn * 128 + wn0 + j * 16 + fm;
      const float bs = bias[gcol];
      if (which == 0) {
#pragma unroll
        for (int r = 0; r < 4; ++r) {
          int grow = grow0 + r;
          float q = (acc[i][j][r] + bs) * (1.f / 16.f);
          size_t o = ((size_t)((grow >> 7) * 32 + (gcol >> 3))) * 1024 + (grow & 127) * 8 + (gcol & 7);
          u16 h = f2bf(q); Qh[o] = h; Ql[o] = f2bf(q - bf2f(h));
        }
      } else if (which == 1) {
        u16 th[4], tl[4];
#pragma unroll
        for (int r = 0; r < 4; ++r) {
          int grow = grow0 + r, sb = grow & (SS - 1);
          float cj = (1.0f - exp2f((float)(sb + 1) * LOG2G)) * INV1MG;
          float kq = (acc[i][j][r] + bs) * rsqrtf(cj);
          size_t o = ((size_t)((grow >> 7) * 32 + (gcol >> 3))) * 1024 + (grow & 127) * 8 + (gcol & 7);
          u16 h = f2bf(kq), l = f2bf(kq - bf2f(h));
          Kh[o] = h; Kl[o] = l; th[r] = h; tl[r] = l;
        }
        int b = grow0 >> 12, sb0 = grow0 & (SS - 1);
        size_t o = ((size_t)((b * 2 + (gcol >> 7)) * 512 + (sb0 >> 3))) * 1024 + (gcol & 127) * 8 + (sb0 & 7);
        uint2 ph, pl;
        ph.x = (u32)th[0] | ((u32)th[1] << 16); ph.y = (u32)th[2] | ((u32)th[3] << 16);
        pl.x = (u32)tl[0] | ((u32)tl[1] << 16); pl.y = (u32)tl[2] | ((u32)tl[3] << 16);
        *(uint2*)&KTh[o] = ph; *(uint2*)&KTl[o] = pl;
      } else {
        int b = grow0 >> 12, sb0 = grow0 & (SS - 1);
        float4 w = {acc[i][j][0] + bs, acc[i][j][1] + bs, acc[i][j][2] + bs, acc[i][j][3] + bs};
        *(float4*)&VT32[(size_t)b * DD * SS + (size_t)gcol * SS + sb0] = w;
      }
    }
}

// ---------------------------------------------------------------------------
// 2) per-chunk vector state from KT packed (weighted sum, no recurrence)
__global__ __launch_bounds__(256) void local_vec_kernel(
    const u16* __restrict__ KTh, const u16* __restrict__ KTl, float* __restrict__ lVec)
{
  const int chunk = blockIdx.x, b = chunk >> 4, c = chunk & 15;
  const int t = threadIdx.x;
  __shared__ float wt[256];
  wt[t] = exp2f((float)(255 - t) * LOG2G);
  __syncthreads();
  const int pd = t >> 7, dl = t & 127;
  float s = 0.f;
  for (int k8 = 0; k8 < 32; ++k8) {
    size_t o = ((size_t)((b * 2 + pd) * 512 + c * 32 + k8)) * 1024 + dl * 8;
    short8 hv = *(const short8*)&KTh[o];
    short8 lv = *(const short8*)&KTl[o];
#pragma unroll
    for (int u = 0; u < 8; ++u)
      s = fmaf(bf2f((u16)hv[u]) + bf2f((u16)lv[u]), wt[k8 * 8 + u], s);
  }
  lVec[(size_t)chunk * DD + t] = s;
}

__global__ __launch_bounds__(256) void combine_vec_kernel(
    const float* __restrict__ lVec, float* __restrict__ cVec)
{
  const int b = blockIdx.x;
  const int d = threadIdx.x;
  const float gL = powf(GAMMA, (float)LL);
  float s = 0.f;
  for (int c = 0; c < NCH; ++c) {
    cVec[(size_t)(b * NCH + c) * DD + d] = s;
    s = gL * s + lVec[(size_t)(b * NCH + c) * DD + d];
  }
}

// ---------------------------------------------------------------------------
// 3) Sg = mask * (Q~.K~) * g^(il-jl), packed split (rows il, k jl)
__global__ __launch_bounds__(256) void scores_kernel(
    const u16* __restrict__ Qh, const u16* __restrict__ Ql,
    const u16* __restrict__ Kh, const u16* __restrict__ Kl,
    u16* __restrict__ Sgh, u16* __restrict__ Sgl)
{
  const int chunk = blockIdx.x, b = chunk >> 4, c = chunk & 15;
  const int ty = blockIdx.y;
  const int m0 = (ty == 0) ? 0 : 128;
  const int n0 = (ty == 2) ? 128 : 0;
  __shared__ u16 Ah[4096], Al[4096], Bh[4096], Bl[4096];
  const int tid = threadIdx.x, lane = tid & 63, wave = tid >> 6;
  const int wm0 = (wave >> 1) * 64, wn0 = (wave & 1) * 64;
  const int fm = lane & 15, fq = lane >> 4;
  const u16* QhP = Qh + (size_t)((b * SS + c * LL + m0) >> 7) * 32768;
  const u16* QlP = Ql + (size_t)((b * SS + c * LL + m0) >> 7) * 32768;
  const u16* KhP = Kh + (size_t)((b * SS + c * LL + n0) >> 7) * 32768;
  const u16* KlP = Kl + (size_t)((b * SS + c * LL + n0) >> 7) * 32768;
  f32x4 acc[4][4];
#pragma unroll
  for (int i = 0; i < 4; ++i)
#pragma unroll
    for (int j = 0; j < 4; ++j) acc[i][j] = (f32x4){0.f, 0.f, 0.f, 0.f};
  for (int ks = 0; ks < 8; ++ks) {
    __syncthreads();
    if (wave == 0) stage8k(QhP + ks * 4096, Ah, lane);
    if (wave == 1) stage8k(QlP + ks * 4096, Al, lane);
    if (wave == 2) stage8k(KhP + ks * 4096, Bh, lane);
    if (wave == 3) stage8k(KlP + ks * 4096, Bl, lane);
    __syncthreads();
    mfma_step_slab(Ah, Al, Bh, Bl, wm0, wn0, fm, fq, acc);
  }
  const int ps = chunk * 2 + (m0 >> 7);
#pragma unroll
  for (int i = 0; i < 4; ++i)
#pragma unroll
    for (int j = 0; j < 4; ++j) {
      const int il0 = m0 + wm0 + i * 16 + fq * 4;
      const int jl = n0 + wn0 + j * 16 + fm;
#pragma unroll
      for (int r = 0; r < 4; ++r) {
        int il = il0 + r;
        float v = (jl <= il) ? acc[i][j][r] * exp2f((float)(il - jl) * LOG2G) : 0.f;
        size_t o = ((size_t)(ps * 32 + (jl >> 3))) * 1024 + (il & 127) * 8 + (jl & 7);
        u16 h = f2bf(v); Sgh[o] = h; Sgl[o] = f2bf(v - bf2f(h));
      }
    }
}

// ---------------------------------------------------------------------------
// 4) denom: rs = g^(il+1)*(Q~.cVec) + rowsum(Sg); denom = max(|rs|,1)
__global__ __launch_bounds__(256) void rs_denom_kernel(
    const u16* __restrict__ Sgh, const u16* __restrict__ Sgl,
    const u16* __restrict__ Qh, const u16* __restrict__ Ql,
    const float* __restrict__ cVec, float* __restrict__ denom)
{
  const int p = blockIdx.x;  // 128 panels
  const int half = p & 1, c = (p >> 1) & 15, b = p >> 5;
  const int tid = threadIdx.x, lane = tid & 63, wave = tid >> 6;
  __shared__ float cv[256];
  cv[tid] = cVec[(size_t)(b * NCH + c) * DD + tid];
  __syncthreads();
  const int k8 = lane & 31, sub = lane >> 5;
  const int nslab = half ? 32 : 16;
  const size_t sgbase = (size_t)p * 32768;
  const size_t qbase = (size_t)(b * 32 + c * 2 + half) * 32768;
  for (int rp = 0; rp < 16; ++rp) {
    int r = wave * 32 + rp * 2 + sub;
    float rsum = 0.f, dt = 0.f;
    {
      size_t oq = qbase + (size_t)k8 * 1024 + r * 8;
      short8 qh = *(const short8*)&Qh[oq];
      short8 ql = *(const short8*)&Ql[oq];
#pragma unroll
      for (int u = 0; u < 8; ++u)
        dt = fmaf(bf2f((u16)qh[u]) + bf2f((u16)ql[u]), cv[k8 * 8 + u], dt);
    }
    if (k8 < nslab) {
      size_t os = sgbase + (size_t)k8 * 1024 + r * 8;
      short8 sh = *(const short8*)&Sgh[os];
      short8 sl = *(const short8*)&Sgl[os];
#pragma unroll
      for (int u = 0; u < 8; ++u)
        rsum += bf2f((u16)sh[u]) + bf2f((u16)sl[u]);
    }
#pragma unroll
    for (int off = 16; off >= 1; off >>= 1) {
      rsum += __shfl_down(rsum, off, 32);
      dt += __shfl_down(dt, off, 32);
    }
    if ((lane & 31) == 0) {
      int il = half * 128 + r;
      float rs = exp2f((float)(il + 1) * LOG2G) * dt + rsum;
      denom[(size_t)b * SS + c * LL + il] = fmaxf(fabsf(rs), 1.0f);
    }
  }
}

// ---------------------------------------------------------------------------
// 5) Vd^T = V^T/denom, Vw^T = Vd^T * g^(L-1-jl): packed splits
__global__ __launch_bounds__(256) void vscale_kernel(
    const float* __restrict__ VT32, const float* __restrict__ denom,
    u16* __restrict__ VdTh, u16* __restrict__ VdTl,
    u16* __restrict__ VwTh, u16* __restrict__ VwTl)
{
  const int x = blockIdx.x;  // 256
  const int b = x >> 6, pd = (x >> 5) & 1, sg = x & 31;
  const int t = threadIdx.x;
  for (int pass = 0; pass < 8; ++pass) {
    int s8 = sg * 16 + pass * 2 + (t >> 7);
    int el = t & 127;
    const float* src = &VT32[(size_t)b * DD * SS + (size_t)(pd * 128 + el) * SS + s8 * 8];
    float4 v0 = *(const float4*)src, v1 = *(const float4*)(src + 4);
    float vv[8] = {v0.x, v0.y, v0.z, v0.w, v1.x, v1.y, v1.z, v1.w};
    const float* dn = &denom[(size_t)b * SS + s8 * 8];
    int sl0 = (s8 * 8) & 255;
    u16 dh[8], dl_[8], wh[8], wl[8];
#pragma unroll
    for (int u = 0; u < 8; ++u) {
      float vd = vv[u] / dn[u];
      float w = exp2f((float)(255 - (sl0 + u)) * LOG2G);
      float vw = vd * w;
      u16 h = f2bf(vd); dh[u] = h; dl_[u] = f2bf(vd - bf2f(h));
      u16 h2 = f2bf(vw); wh[u] = h2; wl[u] = f2bf(vw - bf2f(h2));
    }
    size_t o = ((size_t)((b * 2 + pd) * 512 + s8)) * 1024 + el * 8;
    *(short8*)&VdTh[o] = *(short8*)dh; *(short8*)&VdTl[o] = *(short8*)dl_;
    *(short8*)&VwTh[o] = *(short8*)wh; *(short8*)&VwTl[o] = *(short8*)wl;
  }
}

// ---------------------------------------------------------------------------
// 6) lMatT[e][d] = sum_jl Vw[jl,e] K~[jl,d]
__global__ __launch_bounds__(256) void lmat_kernel(
    const u16* __restrict__ VwTh, const u16* __restrict__ VwTl,
    const u16* __restrict__ KTh, const u16* __restrict__ KTl,
    float* __restrict__ lMatT)
{
  const int chunk = blockIdx.x, b = chunk >> 4, c = chunk & 15;
  const int ty = blockIdx.y;
  const int m0 = (ty >> 1) * 128, n0 = (ty & 1) * 128;
  __shared__ u16 Ah[4096], Al[4096], Bh[4096], Bl[4096];
  const int tid = threadIdx.x, lane = tid & 63, wave = tid >> 6;
  const int wm0 = (wave >> 1) * 64, wn0 = (wave & 1) * 64;
  const int fm = lane & 15, fq = lane >> 4;
  const u16* AhP = VwTh + ((size_t)(b * 2 + (m0 >> 7)) * 512 + c * 32) * 1024;
  const u16* AlP = VwTl + ((size_t)(b * 2 + (m0 >> 7)) * 512 + c * 32) * 1024;
  const u16* BhP = KTh + ((size_t)(b * 2 + (n0 >> 7)) * 512 + c * 32) * 1024;
  const u16* BlP = KTl + ((size_t)(b * 2 + (n0 >> 7)) * 512 + c * 32) * 1024;
  f32x4 acc[4][4];
#pragma unroll
  for (int i = 0; i < 4; ++i)
#pragma unroll
    for (int j = 0; j < 4; ++j) acc[i][j] = (f32x4){0.f, 0.f, 0.f, 0.f};
  for (int ks = 0; ks < 8; ++ks) {
    __syncthreads();
    if (wave == 0) stage8k(AhP + ks * 4096, Ah, lane);
    if (wave == 1) stage8k(AlP + ks * 4096, Al, lane);
    if (wave == 2) stage8k(BhP + ks * 4096, Bh, lane);
    if (wave == 3) stage8k(BlP + ks * 4096, Bl, lane);
    __syncthreads();
    mfma_step_slab(Ah, Al, Bh, Bl, wm0, wn0, fm, fq, acc);
  }
#pragma unroll
  for (int i = 0; i < 4; ++i)
#pragma unroll
    for (int j = 0; j < 4; ++j)
#pragma unroll
      for (int r = 0; r < 4; ++r) {
        int e = m0 + wm0 + i * 16 + fq * 4 + r;
        int d = n0 + wn0 + j * 16 + fm;
        lMatT[(size_t)chunk * 65536 + (size_t)e * 256 + d] = acc[i][j][r];
      }
}

// 7) carry scan -> cM packed split (rows e, k d)
__global__ __launch_bounds__(256) void combine_mat_kernel(
    const float* __restrict__ lMatT, u16* __restrict__ cMh, u16* __restrict__ cMl)
{
  const int t = blockIdx.x * 256 + threadIdx.x;  // 32768: b x k8 x e
  const int b = t >> 13, rem = t & 8191;
  const int k8 = rem >> 8, e = rem & 255;
  const float gL = powf(GAMMA, (float)LL);
  float s[8] = {0.f, 0.f, 0.f, 0.f, 0.f, 0.f, 0.f, 0.f};
  for (int ch = 0; ch < 16; ++ch) {
    size_t ro = (size_t)(b * 16 + ch) * 65536 + (size_t)e * 256 + k8 * 8;
    float4 a0 = *(const float4*)&lMatT[ro];
    float4 a1 = *(const float4*)&lMatT[ro + 4];
    float vals[8] = {a0.x, a0.y, a0.z, a0.w, a1.x, a1.y, a1.z, a1.w};
    u16 hh[8], ll[8];
#pragma unroll
    for (int u = 0; u < 8; ++u) {
      u16 h = f2bf(s[u]); hh[u] = h; ll[u] = f2bf(s[u] - bf2f(h));
    }
    size_t wo = ((size_t)(((b * 16 + ch) * 2 + (e >> 7)) * 32 + k8)) * 1024 + (e & 127) * 8;
    *(short8*)&cMh[wo] = *(short8*)hh;
    *(short8*)&cMl[wo] = *(short8*)ll;
#pragma unroll
    for (int u = 0; u < 8; ++u) s[u] = gL * s[u] + vals[u];
  }
}

// ---------------------------------------------------------------------------
// 8) out = g^(il+1) * Q~ @ cM^T + Sg @ Vd
__global__ __launch_bounds__(256) void out_kernel(
    const u16* __restrict__ Qh, const u16* __restrict__ Ql,
    const u16* __restrict__ cMh, const u16* __restrict__ cMl,
    const u16* __restrict__ Sgh, const u16* __restrict__ Sgl,
    const u16* __restrict__ VdTh, const u16* __restrict__ VdTl,
    float* __restrict__ out)
{
  const int chunk = blockIdx.x, b = chunk >> 4, c = chunk & 15;
  const int ty = blockIdx.y;
  const int m0 = (ty >> 1) * 128, n0 = (ty & 1) * 128;
  __shared__ u16 Ah[4096], Al[4096], Bh[4096], Bl[4096];
  const int tid = threadIdx.x, lane = tid & 63, wave = tid >> 6;
  const int wm0 = (wave >> 1) * 64, wn0 = (wave & 1) * 64;
  const int fm = lane & 15, fq = lane >> 4;
  f32x4 acc[4][4];
#pragma unroll
  for (int i = 0; i < 4; ++i)
#pragma unroll
    for (int j = 0; j < 4; ++j) acc[i][j] = (f32x4){0.f, 0.f, 0.f, 0.f};
  {  // inter: A = Q panel, B = cM panel
    const u16* AhP = Qh + (size_t)(b * 32 + c * 2 + (m0 >> 7)) * 32768;
    const u16* AlP = Ql + (size_t)(b * 32 + c * 2 + (m0 >> 7)) * 32768;
    const u16* BhP = cMh + (size_t)(chunk * 2 + (n0 >> 7)) * 32768;
    const u16* BlP = cMl + (size_t)(chunk * 2 + (n0 >> 7)) * 32768;
    for (int ks = 0; ks < 8; ++ks) {
      __syncthreads();
      if (wave == 0) stage8k(AhP + ks * 4096, Ah, lane);
      if (wave == 1) stage8k(AlP + ks * 4096, Al, lane);
      if (wave == 2) stage8k(BhP + ks * 4096, Bh, lane);
      if (wave == 3) stage8k(BlP + ks * 4096, Bl, lane);
      __syncthreads();
      mfma_step_slab(Ah, Al, Bh, Bl, wm0, wn0, fm, fq, acc);
    }
  }
#pragma unroll
  for (int i = 0; i < 4; ++i)
#pragma unroll
    for (int r = 0; r < 4; ++r) {
      int il = m0 + wm0 + i * 16 + fq * 4 + r;
      float sc = exp2f((float)(il + 1) * LOG2G);
#pragma unroll
      for (int j = 0; j < 4; ++j) acc[i][j][r] *= sc;
    }
  {  // intra: A = Sg panel, B = VdT panel; k bounded by causality
    const u16* AhP = Sgh + (size_t)(chunk * 2 + (m0 >> 7)) * 32768;
    const u16* AlP = Sgl + (size_t)(chunk * 2 + (m0 >> 7)) * 32768;
    const u16* BhP = VdTh + ((size_t)(b * 2 + (n0 >> 7)) * 512 + c * 32) * 1024;
    const u16* BlP = VdTl + ((size_t)(b * 2 + (n0 >> 7)) * 512 + c * 32) * 1024;
    const int nks = (m0 >> 5) + 4;  // 4 or 8
    for (int ks = 0; ks < nks; ++ks) {
      __syncthreads();
      if (wave == 0) stage8k(AhP + ks * 4096, Ah, lane);
      if (wave == 1) stage8k(AlP + ks * 4096, Al, lane);
      if (wave == 2) stage8k(BhP + ks * 4096, Bh, lane);
      if (wave == 3) stage8k(BlP + ks * 4096, Bl, lane);
      __syncthreads();
      mfma_step_slab(Ah, Al, Bh, Bl, wm0, wn0, fm, fq, acc);
    }
  }
#pragma unroll
  for (int i = 0; i < 4; ++i)
#pragma unroll
    for (int j = 0; j < 4; ++j)
#pragma unroll
      for (int r = 0; r < 4; ++r) {
        int il = m0 + wm0 + i * 16 + fq * 4 + r;
        int e = n0 + wn0 + j * 16 + fm;
        out[(size_t)(b * SS + c * LL + il) * DD + e] = acc[i][j][r];
      }
}

// ---------------------------------------------------------------------------
extern "C" void kernel_launch(void* const* d_in, const int* in_sizes, int n_in,
                              void* d_out, int out_size, void* d_ws, size_t ws_size,
                              hipStream_t stream) {
  const float* xq = (const float*)d_in[0];
  const float* xk = (const float*)d_in[1];
  const float* xv = (const float*)d_in[2];
  const float* Wq = (const float*)d_in[3];
  const float* bq = (const float*)d_in[4];
  const float* Wk = (const float*)d_in[5];
  const float* bk = (const float*)d_in[6];
  const float* Wv = (const float*)d_in[7];
  const float* bv = (const float*)d_in[8];
  float* out = (float*)d_out;

  char* p = (char*)d_ws;
  const size_t H16 = (size_t)BB * SS * DD * 2;  // 8 MB
  u16* Qh = (u16*)p; p += H16;   u16* Ql = (u16*)p; p += H16;
  u16* Kh = (u16*)p; p += H16;   u16* Kl = (u16*)p; p += H16;
  u16* KTh = (u16*)p; p += H16;  u16* KTl = (u16*)p; p += H16;
  u16* VdTh = (u16*)p; p += H16; u16* VdTl = (u16*)p; p += H16;
  u16* VwTh = (u16*)p; p += H16; u16* VwTl = (u16*)p; p += H16;
  u16* Sgh = (u16*)p; p += H16;  u16* Sgl = (u16*)p; p += H16;
  u16* cMh = (u16*)p; p += H16;  u16* cMl = (u16*)p; p += H16;
  float* VT32 = (float*)p; p += (size_t)BB * SS * DD * 4;
  float* lMatT = (float*)p; p += (size_t)BB * NCH * DD * DD * 4;
  u16* Wth = (u16*)p; p += (size_t)3 * DD * DD * 2;
  u16* Wtl = (u16*)p; p += (size_t)3 * DD * DD * 2;
  float* denom = (float*)p; p += (size_t)BB * SS * 4;
  float* lVec = (float*)p; p += (size_t)BB * NCH * DD * 4;
  float* cVec = (float*)p; p += (size_t)BB * NCH * DD * 4;

  packW_kernel<<<dim3(3, 2), 256, 0, stream>>>(Wq, Wk, Wv, Wth, Wtl);
  proj_kernel<<<dim3(BB * SS / 128, 2, 3), 256, 0, stream>>>(
      xq, xk, xv, Wth, Wtl, bq, bk, bv, Qh, Ql, Kh, Kl, KTh, KTl, VT32);
  local_vec_kernel<<<BB * NCH, 256, 0, stream>>>(KTh, KTl, lVec);
  combine_vec_kernel<<<BB, 256, 0, stream>>>(lVec, cVec);
  scores_kernel<<<dim3(BB * NCH, 3), 256, 0, stream>>>(Qh, Ql, Kh, Kl, Sgh, Sgl);
  rs_denom_kernel<<<BB * NCH * 2, 256, 0, stream>>>(Sgh, Sgl, Qh, Ql, cVec, denom);
  vscale_kernel<<<256, 256, 0, stream>>>(VT32, denom, VdTh, VdTl, VwTh, VwTl);
  lmat_kernel<<<dim3(BB * NCH, 4), 256, 0, stream>>>(VwTh, VwTl, KTh, KTl, lMatT);
  combine_mat_kernel<<<128, 256, 0, stream>>>(lMatT, cMh, cMl);
  out_kernel<<<dim3(BB * NCH, 4), 256, 0, stream>>>(
      Qh, Ql, cMh, cMl, Sgh, Sgl, VdTh, VdTl, out);
}